// Round 3
// baseline (418.162 us; speedup 1.0000x reference)
//
#include <hip/hip_runtime.h>

// DifferentiableEKF, temporally parallelized (Sarkka & Garcia-Fernandez associative
// filtering elements). B=8192 rows, T=2048 steps. One 64-lane wave per row; each lane
// owns a 32-step segment: build segment element -> wave-level shfl scan (6 rounds) ->
// boundary state from prior -> exact sequential replay of the 32 steps.
//
// R3: zero LDS. (h,sigma) are converted to (a,scale) on load and live in registers
// (32 x float2); the replay overwrites them 1:1 with (x0,x1) and a final burst of 16
// dwordx4 stores emits the lane's contiguous 256B output span (L2 write-combines).
// LDS 16.9KB -> 0 lifts occupancy from ~7 blocks/CU (LDS-capped) to VGPR-capped
// 4 waves/SIMD via __launch_bounds__(64,4).

#define NB 8192
#define NT 2048
#define SEG 32      // timesteps per lane
#define NC4 8       // float4 chunks per lane (SEG/4)

__device__ __forceinline__ float frcp(float x)  { return __builtin_amdgcn_rcpf(x); }
__device__ __forceinline__ float fexp2(float x) { return __builtin_amdgcn_exp2f(x); }

// Filtering element: posterior given segment obs as function of prior (m,P):
//   m' = A (I + P J)^-1 (m + P eta) + b ;  P' = A (I + P J)^-1 P A^T + C
struct Elt {
    float A00, A01, A10, A11;
    float b0, b1;
    float C00, C01, C11;   // symmetric
    float e0, e1;          // eta
    float J00, J01, J11;   // symmetric
};

// General associative combine: i = earlier, j = later.
__device__ __forceinline__ Elt combine(const Elt& i, const Elt& j)
{
    // D = I + C_i J_j   (det >= 1: products of PSD matrices)
    float D00 = 1.0f + __builtin_fmaf(i.C00, j.J00, i.C01 * j.J01);
    float D01 =        __builtin_fmaf(i.C00, j.J01, i.C01 * j.J11);
    float D10 =        __builtin_fmaf(i.C01, j.J00, i.C11 * j.J01);
    float D11 = 1.0f + __builtin_fmaf(i.C01, j.J01, i.C11 * j.J11);
    float idet = frcp(__builtin_fmaf(D00, D11, -D01 * D10));
    float V00 =  D11 * idet, V01 = -D01 * idet;
    float V10 = -D10 * idet, V11 =  D00 * idet;          // V = D^-1
    // E = A_j V
    float E00 = __builtin_fmaf(j.A00, V00, j.A01 * V10);
    float E01 = __builtin_fmaf(j.A00, V01, j.A01 * V11);
    float E10 = __builtin_fmaf(j.A10, V00, j.A11 * V10);
    float E11 = __builtin_fmaf(j.A10, V01, j.A11 * V11);
    Elt r;
    // A = E A_i
    r.A00 = __builtin_fmaf(E00, i.A00, E01 * i.A10);
    r.A01 = __builtin_fmaf(E00, i.A01, E01 * i.A11);
    r.A10 = __builtin_fmaf(E10, i.A00, E11 * i.A10);
    r.A11 = __builtin_fmaf(E10, i.A01, E11 * i.A11);
    // b = E (b_i + C_i eta_j) + b_j
    float t0 = i.b0 + __builtin_fmaf(i.C00, j.e0, i.C01 * j.e1);
    float t1 = i.b1 + __builtin_fmaf(i.C01, j.e0, i.C11 * j.e1);
    r.b0 = j.b0 + __builtin_fmaf(E00, t0, E01 * t1);
    r.b1 = j.b1 + __builtin_fmaf(E10, t0, E11 * t1);
    // C = E C_i A_j^T + C_j   (symmetric)
    float T00 = __builtin_fmaf(E00, i.C00, E01 * i.C01);
    float T01 = __builtin_fmaf(E00, i.C01, E01 * i.C11);
    float T10 = __builtin_fmaf(E10, i.C00, E11 * i.C01);
    float T11 = __builtin_fmaf(E10, i.C01, E11 * i.C11);
    r.C00 = j.C00 + __builtin_fmaf(T00, j.A00, T01 * j.A01);
    r.C01 = j.C01 + __builtin_fmaf(T00, j.A10, T01 * j.A11);
    r.C11 = j.C11 + __builtin_fmaf(T10, j.A10, T11 * j.A11);
    // eta = A_i^T V^T (eta_j - J_j b_i) + eta_i
    float u0 = j.e0 - __builtin_fmaf(j.J00, i.b0, j.J01 * i.b1);
    float u1 = j.e1 - __builtin_fmaf(j.J01, i.b0, j.J11 * i.b1);
    float w0 = __builtin_fmaf(V00, u0, V10 * u1);
    float w1 = __builtin_fmaf(V01, u0, V11 * u1);
    r.e0 = i.e0 + __builtin_fmaf(i.A00, w0, i.A10 * w1);
    r.e1 = i.e1 + __builtin_fmaf(i.A01, w0, i.A11 * w1);
    // J = A_i^T V^T J_j A_i + J_i   (symmetric)
    float W00 = __builtin_fmaf(V00, j.J00, V10 * j.J01);
    float W01 = __builtin_fmaf(V00, j.J01, V10 * j.J11);
    float W10 = __builtin_fmaf(V01, j.J00, V11 * j.J01);
    float W11 = __builtin_fmaf(V01, j.J01, V11 * j.J11);
    float X00 = __builtin_fmaf(i.A00, W00, i.A10 * W10);
    float X01 = __builtin_fmaf(i.A00, W01, i.A10 * W11);
    float X10 = __builtin_fmaf(i.A01, W00, i.A11 * W10);
    float X11 = __builtin_fmaf(i.A01, W01, i.A11 * W11);
    r.J00 = i.J00 + __builtin_fmaf(X00, i.A00, X01 * i.A10);
    r.J01 = i.J01 + __builtin_fmaf(X00, i.A01, X01 * i.A11);
    r.J11 = i.J11 + __builtin_fmaf(X10, i.A01, X11 * i.A11);
    return r;
}

// (h, sigma) -> (a, scale)
__device__ __forceinline__ float2 cvt_asc(float h, float sg)
{
    float ee = fexp2(__builtin_fmaf(h, -14.4269504088896f, 7.2134752044448f));
    float a  = __builtin_fmaf(0.5f, frcp(1.0f + ee), 0.5f);
    float sc = fmaxf(100.0f * sg, 1.0f);
    return make_float2(a, sc);
}

// Append one timestep (later) to accumulated element E (earlier), using the step's
// rank-1 structure (Sherman-Morrison). a/scale precomputed.
__device__ __forceinline__ void append_step(Elt& E, float z, float a, float sc)
{
    float q  = 0.1f * sc;
    float r  = sc + 1e-6f;                 // effective R (matches ref's S+1e-6)
    float Sinv = frcp(q + r);
    float u = q * Sinv;
    float v = r * Sinv;

    // w = [1, a];  cw = C w ; g = Sinv * cw ; D = I + g w^T
    float cw0 = __builtin_fmaf(a, E.C01, E.C00);
    float cw1 = __builtin_fmaf(a, E.C11, E.C01);
    float g0 = Sinv * cw0, g1 = Sinv * cw1;
    float rho = frcp(__builtin_fmaf(a, g1, 1.0f + g0));   // 1/(1 + w.g)
    float gp0 = rho * g0, gp1 = rho * g1;

    float s0 = __builtin_fmaf(a, E.A10, E.A00);           // s = A^T w
    float s1 = __builtin_fmaf(a, E.A11, E.A01);

    float wb0  = __builtin_fmaf(a, E.b1, E.b0);           // w . b (old)
    float beta = Sinv * (z - wb0);
    float bp0  = __builtin_fmaf(z, g0, E.b0);             // b + z g  (= b + C eta_s)
    float bp1  = __builtin_fmaf(z, g1, E.b1);

    // A_new = A_s (A - gp s^T),  A_s = [[v, v a],[0,1]]
    float N00 = __builtin_fmaf(-gp0, s0, E.A00);
    float N01 = __builtin_fmaf(-gp0, s1, E.A01);
    float N10 = __builtin_fmaf(-gp1, s0, E.A10);
    float N11 = __builtin_fmaf(-gp1, s1, E.A11);
    float A00n = v * __builtin_fmaf(a, N10, N00);
    float A01n = v * __builtin_fmaf(a, N11, N01);
    // b_new = A_s (bp - gp (w.bp)) + [u z, 0]
    float wbp = __builtin_fmaf(a, bp1, bp0);
    float t0b = __builtin_fmaf(-gp0, wbp, bp0);
    float t1b = __builtin_fmaf(-gp1, wbp, bp1);
    float b0n = __builtin_fmaf(v, __builtin_fmaf(a, t1b, t0b), u * z);
    // C_new = A_s (C - gp cw^T) A_s^T + diag(v q, q)
    float M00 = __builtin_fmaf(-gp0, cw0, E.C00);
    float M01 = __builtin_fmaf(-gp0, cw1, E.C01);
    float M11 = __builtin_fmaf(-gp1, cw1, E.C11);
    float tc0 = __builtin_fmaf(a, M01, M00);
    float tc1 = __builtin_fmaf(a, M11, M01);
    float C00n = v * __builtin_fmaf(v, __builtin_fmaf(a, tc1, tc0), q);
    float C01n = v * tc1;
    float C11n = M11 + q;
    // eta_new = eta + beta*rho * s ;  J_new = J + rho*Sinv * s s^T
    float br  = beta * rho;
    float e0n = __builtin_fmaf(br, s0, E.e0);
    float e1n = __builtin_fmaf(br, s1, E.e1);
    float kap = rho * Sinv;
    float ks0 = kap * s0, ks1 = kap * s1;
    float J00n = __builtin_fmaf(ks0, s0, E.J00);
    float J01n = __builtin_fmaf(ks0, s1, E.J01);
    float J11n = __builtin_fmaf(ks1, s1, E.J11);

    E.A00 = A00n; E.A01 = A01n; E.A10 = N10; E.A11 = N11;
    E.b0 = b0n;  E.b1 = t1b;
    E.C00 = C00n; E.C01 = C01n; E.C11 = C11n;
    E.e0 = e0n;  E.e1 = e1n;
    E.J00 = J00n; E.J01 = J01n; E.J11 = J11n;
}

__device__ __forceinline__ Elt shfl_up_elt(const Elt& x, int d)
{
    Elt r;
    r.A00 = __shfl_up(x.A00, d, 64); r.A01 = __shfl_up(x.A01, d, 64);
    r.A10 = __shfl_up(x.A10, d, 64); r.A11 = __shfl_up(x.A11, d, 64);
    r.b0  = __shfl_up(x.b0,  d, 64); r.b1  = __shfl_up(x.b1,  d, 64);
    r.C00 = __shfl_up(x.C00, d, 64); r.C01 = __shfl_up(x.C01, d, 64);
    r.C11 = __shfl_up(x.C11, d, 64);
    r.e0  = __shfl_up(x.e0,  d, 64); r.e1  = __shfl_up(x.e1,  d, 64);
    r.J00 = __shfl_up(x.J00, d, 64); r.J01 = __shfl_up(x.J01, d, 64);
    r.J11 = __shfl_up(x.J11, d, 64);
    return r;
}

__device__ __forceinline__ void replay_step(float z, float a, float sc,
        float& x0, float& x1, float& p00, float& p01, float& p11)
{
    float q  = 0.1f * sc;
    float rp = sc + 1e-6f;
    float qr = q + rp;
    float tA = __builtin_fmaf(a + a, p01, p00);
    float tB = __builtin_fmaf(a * a, p11, qr);
    float Seff = tA + tB;
    float Sinv = frcp(Seff);
    float pp00 = Seff - rp;
    float pp01 = __builtin_fmaf(a, p11, p01);
    float pp11 = p11 + q;
    float K0 = pp00 * Sinv, K1 = pp01 * Sinv;
    float xp0 = __builtin_fmaf(a, x1, x0);
    float y = z - xp0;
    x0 = __builtin_fmaf(K0, y, xp0);
    x1 = __builtin_fmaf(K1, y, x1);
    p00 = __builtin_fmaf(-K0, pp00, pp00);
    p01 = __builtin_fmaf(-K0, pp01, pp01);
    p11 = __builtin_fmaf(-K1, pp01, pp11);
}

__global__ __launch_bounds__(64, 4)
void ekf_kernel(const float* __restrict__ price,
                const float* __restrict__ hurst,
                const float* __restrict__ sigv,
                float* __restrict__ out)
{
    const int row  = blockIdx.x;            // one row per 64-thread block (one wave)
    const int lane = threadIdx.x;

    const float4* __restrict__ pr4 = (const float4*)(price + (size_t)row * NT) + lane * NC4;
    const float4* __restrict__ hu4 = (const float4*)(hurst + (size_t)row * NT) + lane * NC4;
    const float4* __restrict__ sg4 = (const float4*)(sigv  + (size_t)row * NT) + lane * NC4;

    // ---------- Phase 0: load h/sigma (batched, line-merged) and convert in place ----------
    float2 asc[SEG];                        // (a, scale) per local step: 64 VGPRs
    {
        float4 hb[NC4], sb[NC4];
#pragma unroll
        for (int c = 0; c < NC4; ++c) hb[c] = hu4[c];
#pragma unroll
        for (int c = 0; c < NC4; ++c) sb[c] = sg4[c];
#pragma unroll
        for (int c = 0; c < NC4; ++c) {
            asc[4 * c + 0] = cvt_asc(hb[c].x, sb[c].x);
            asc[4 * c + 1] = cvt_asc(hb[c].y, sb[c].y);
            asc[4 * c + 2] = cvt_asc(hb[c].z, sb[c].z);
            asc[4 * c + 3] = cvt_asc(hb[c].w, sb[c].w);
        }
    }

    // ---------- Phase 1: load price, build this lane's 32-step segment element ----------
    float z0l, z1l;
    Elt E;
    E.A00 = 1.0f; E.A01 = 0.0f; E.A10 = 0.0f; E.A11 = 1.0f;
    E.b0 = 0.0f; E.b1 = 0.0f;
    E.C00 = 0.0f; E.C01 = 0.0f; E.C11 = 0.0f;
    E.e0 = 0.0f; E.e1 = 0.0f;
    E.J00 = 0.0f; E.J01 = 0.0f; E.J11 = 0.0f;
    {
        float4 zb[NC4];
#pragma unroll
        for (int c = 0; c < NC4; ++c) zb[c] = pr4[c];
        z0l = zb[0].x; z1l = zb[0].y;       // lane 0's copies give m0
#pragma unroll
        for (int c = 0; c < NC4; ++c) {
            append_step(E, zb[c].x, asc[4 * c + 0].x, asc[4 * c + 0].y);
            append_step(E, zb[c].y, asc[4 * c + 1].x, asc[4 * c + 1].y);
            append_step(E, zb[c].z, asc[4 * c + 2].x, asc[4 * c + 2].y);
            append_step(E, zb[c].w, asc[4 * c + 3].x, asc[4 * c + 3].y);
        }
    }

    // ---------- Phase 2: inclusive wave scan over the 64 segment elements ----------
#pragma unroll
    for (int d = 1; d < 64; d <<= 1) {
        Elt o = shfl_up_elt(E, d);
        Elt c = combine(o, E);
        bool p = (lane >= d);
        E.A00 = p ? c.A00 : E.A00; E.A01 = p ? c.A01 : E.A01;
        E.A10 = p ? c.A10 : E.A10; E.A11 = p ? c.A11 : E.A11;
        E.b0  = p ? c.b0  : E.b0;  E.b1  = p ? c.b1  : E.b1;
        E.C00 = p ? c.C00 : E.C00; E.C01 = p ? c.C01 : E.C01;
        E.C11 = p ? c.C11 : E.C11;
        E.e0  = p ? c.e0  : E.e0;  E.e1  = p ? c.e1  : E.e1;
        E.J00 = p ? c.J00 : E.J00; E.J01 = p ? c.J01 : E.J01;
        E.J11 = p ? c.J11 : E.J11;
    }

    // Exclusive prefix: element covering steps [0, 32*lane)
    Elt ex = shfl_up_elt(E, 1);
    {
        bool l0 = (lane == 0);              // identity element for lane 0
        ex.A00 = l0 ? 1.0f : ex.A00; ex.A01 = l0 ? 0.0f : ex.A01;
        ex.A10 = l0 ? 0.0f : ex.A10; ex.A11 = l0 ? 1.0f : ex.A11;
        ex.b0  = l0 ? 0.0f : ex.b0;  ex.b1  = l0 ? 0.0f : ex.b1;
        ex.C00 = l0 ? 0.0f : ex.C00; ex.C01 = l0 ? 0.0f : ex.C01;
        ex.C11 = l0 ? 0.0f : ex.C11;
        ex.e0  = l0 ? 0.0f : ex.e0;  ex.e1  = l0 ? 0.0f : ex.e1;
        ex.J00 = l0 ? 0.0f : ex.J00; ex.J01 = l0 ? 0.0f : ex.J01;
        ex.J11 = l0 ? 0.0f : ex.J11;
    }

    // ---------- Phase 3: boundary state from prior (m0, P0 = I) ----------
    float m00 = __shfl(z0l, 0, 64);
    float m01 = __shfl(z1l, 0, 64) - m00;   // v0 = (z1 - z0)/dt, dt = 1

    // apply ex to (m0, I): D = I + J_ex ; E1 = A_ex D^-1
    float D00 = 1.0f + ex.J00, D01 = ex.J01, D11 = 1.0f + ex.J11;
    float idet = frcp(__builtin_fmaf(D00, D11, -D01 * D01));
    float V00 =  D11 * idet, V01 = -D01 * idet;
    float V10 = -D01 * idet, V11 =  D00 * idet;
    float E00 = __builtin_fmaf(ex.A00, V00, ex.A01 * V10);
    float E01 = __builtin_fmaf(ex.A00, V01, ex.A01 * V11);
    float E10 = __builtin_fmaf(ex.A10, V00, ex.A11 * V10);
    float E11 = __builtin_fmaf(ex.A10, V01, ex.A11 * V11);
    float t0 = m00 + ex.e0, t1 = m01 + ex.e1;
    float x0 = ex.b0 + __builtin_fmaf(E00, t0, E01 * t1);
    float x1 = ex.b1 + __builtin_fmaf(E10, t0, E11 * t1);
    float p00 = ex.C00 + __builtin_fmaf(E00, ex.A00, E01 * ex.A01);
    float p01 = ex.C01 + __builtin_fmaf(E00, ex.A10, E01 * ex.A11);
    float p11 = ex.C11 + __builtin_fmaf(E10, ex.A10, E11 * ex.A11);

    // ---------- Phase 4: reload price (batched, cache-warm), replay into registers ----------
    float4 o[2 * NC4];                      // (x0,x1) pairs: 64 VGPRs, replaces asc 1:1
    {
        float4 zb[NC4];
#pragma unroll
        for (int c = 0; c < NC4; ++c) zb[c] = pr4[c];
#pragma unroll
        for (int c = 0; c < NC4; ++c) {
            replay_step(zb[c].x, asc[4 * c + 0].x, asc[4 * c + 0].y, x0, x1, p00, p01, p11);
            o[2 * c].x = x0; o[2 * c].y = x1;
            replay_step(zb[c].y, asc[4 * c + 1].x, asc[4 * c + 1].y, x0, x1, p00, p01, p11);
            o[2 * c].z = x0; o[2 * c].w = x1;
            replay_step(zb[c].z, asc[4 * c + 2].x, asc[4 * c + 2].y, x0, x1, p00, p01, p11);
            o[2 * c + 1].x = x0; o[2 * c + 1].y = x1;
            replay_step(zb[c].w, asc[4 * c + 3].x, asc[4 * c + 3].y, x0, x1, p00, p01, p11);
            o[2 * c + 1].z = x0; o[2 * c + 1].w = x1;
        }
    }

    // ---------- Phase 5: burst stores — lane's contiguous 256B span, L2 write-combined ----------
    float4* __restrict__ op4 = (float4*)(out + (size_t)row * (size_t)NT * 2) + lane * (2 * NC4);
#pragma unroll
    for (int i = 0; i < 2 * NC4; ++i) op4[i] = o[i];
}

extern "C" void kernel_launch(void* const* d_in, const int* in_sizes, int n_in,
                              void* d_out, int out_size, void* d_ws, size_t ws_size,
                              hipStream_t stream)
{
    const float* price = (const float*)d_in[0];
    const float* hurst = (const float*)d_in[1];
    const float* sigv  = (const float*)d_in[2];
    float* out = (float*)d_out;

    dim3 grid(NB), block(64);
    hipLaunchKernelGGL(ekf_kernel, grid, block, 0, stream, price, hurst, sigv, out);
}

// Round 4
// 332.240 us; speedup vs baseline: 1.2586x; 1.2586x over previous
//
#include <hip/hip_runtime.h>

// DifferentiableEKF, temporally parallelized (Sarkka & Garcia-Fernandez associative
// filtering elements). B=8192 rows, T=2048 steps. One 64-lane wave per row; each lane
// owns a 32-step segment: build segment element -> wave-level shfl scan (6 rounds) ->
// boundary state from prior -> exact sequential replay of the 32 steps.
//
// R4: back to the R2 LDS-staged structure (R3's register arrays spilled to scratch:
// WRITE 432MB). LDS now stages OUTPUT ONLY, in two 16-step half-passes through an
// 8.4 KB buffer (single wave per block -> wave-synchronous reuse, no barriers).
// Replay recomputes (a,scale) from cache-warm h/sigma reloads instead of staging them.
// LDS 16.9 -> 8.4 KB lifts the residency cap from ~9 to ~19 blocks/CU.

#define NB 8192
#define NT 2048
#define SEG 32      // timesteps per lane
#define NC4 8       // float4 chunks per lane (SEG/4)

__device__ __forceinline__ float frcp(float x)  { return __builtin_amdgcn_rcpf(x); }
__device__ __forceinline__ float fexp2(float x) { return __builtin_amdgcn_exp2f(x); }

// Filtering element: posterior given segment obs as function of prior (m,P):
//   m' = A (I + P J)^-1 (m + P eta) + b ;  P' = A (I + P J)^-1 P A^T + C
struct Elt {
    float A00, A01, A10, A11;
    float b0, b1;
    float C00, C01, C11;   // symmetric
    float e0, e1;          // eta
    float J00, J01, J11;   // symmetric
};

// General associative combine: i = earlier, j = later.
__device__ __forceinline__ Elt combine(const Elt& i, const Elt& j)
{
    // D = I + C_i J_j   (det >= 1: products of PSD matrices)
    float D00 = 1.0f + __builtin_fmaf(i.C00, j.J00, i.C01 * j.J01);
    float D01 =        __builtin_fmaf(i.C00, j.J01, i.C01 * j.J11);
    float D10 =        __builtin_fmaf(i.C01, j.J00, i.C11 * j.J01);
    float D11 = 1.0f + __builtin_fmaf(i.C01, j.J01, i.C11 * j.J11);
    float idet = frcp(__builtin_fmaf(D00, D11, -D01 * D10));
    float V00 =  D11 * idet, V01 = -D01 * idet;
    float V10 = -D10 * idet, V11 =  D00 * idet;          // V = D^-1
    // E = A_j V
    float E00 = __builtin_fmaf(j.A00, V00, j.A01 * V10);
    float E01 = __builtin_fmaf(j.A00, V01, j.A01 * V11);
    float E10 = __builtin_fmaf(j.A10, V00, j.A11 * V10);
    float E11 = __builtin_fmaf(j.A10, V01, j.A11 * V11);
    Elt r;
    // A = E A_i
    r.A00 = __builtin_fmaf(E00, i.A00, E01 * i.A10);
    r.A01 = __builtin_fmaf(E00, i.A01, E01 * i.A11);
    r.A10 = __builtin_fmaf(E10, i.A00, E11 * i.A10);
    r.A11 = __builtin_fmaf(E10, i.A01, E11 * i.A11);
    // b = E (b_i + C_i eta_j) + b_j
    float t0 = i.b0 + __builtin_fmaf(i.C00, j.e0, i.C01 * j.e1);
    float t1 = i.b1 + __builtin_fmaf(i.C01, j.e0, i.C11 * j.e1);
    r.b0 = j.b0 + __builtin_fmaf(E00, t0, E01 * t1);
    r.b1 = j.b1 + __builtin_fmaf(E10, t0, E11 * t1);
    // C = E C_i A_j^T + C_j   (symmetric)
    float T00 = __builtin_fmaf(E00, i.C00, E01 * i.C01);
    float T01 = __builtin_fmaf(E00, i.C01, E01 * i.C11);
    float T10 = __builtin_fmaf(E10, i.C00, E11 * i.C01);
    float T11 = __builtin_fmaf(E10, i.C01, E11 * i.C11);
    r.C00 = j.C00 + __builtin_fmaf(T00, j.A00, T01 * j.A01);
    r.C01 = j.C01 + __builtin_fmaf(T00, j.A10, T01 * j.A11);
    r.C11 = j.C11 + __builtin_fmaf(T10, j.A10, T11 * j.A11);
    // eta = A_i^T V^T (eta_j - J_j b_i) + eta_i
    float u0 = j.e0 - __builtin_fmaf(j.J00, i.b0, j.J01 * i.b1);
    float u1 = j.e1 - __builtin_fmaf(j.J01, i.b0, j.J11 * i.b1);
    float w0 = __builtin_fmaf(V00, u0, V10 * u1);
    float w1 = __builtin_fmaf(V01, u0, V11 * u1);
    r.e0 = i.e0 + __builtin_fmaf(i.A00, w0, i.A10 * w1);
    r.e1 = i.e1 + __builtin_fmaf(i.A01, w0, i.A11 * w1);
    // J = A_i^T V^T J_j A_i + J_i   (symmetric)
    float W00 = __builtin_fmaf(V00, j.J00, V10 * j.J01);
    float W01 = __builtin_fmaf(V00, j.J01, V10 * j.J11);
    float W10 = __builtin_fmaf(V01, j.J00, V11 * j.J01);
    float W11 = __builtin_fmaf(V01, j.J01, V11 * j.J11);
    float X00 = __builtin_fmaf(i.A00, W00, i.A10 * W10);
    float X01 = __builtin_fmaf(i.A00, W01, i.A10 * W11);
    float X10 = __builtin_fmaf(i.A01, W00, i.A11 * W10);
    float X11 = __builtin_fmaf(i.A01, W01, i.A11 * W11);
    r.J00 = i.J00 + __builtin_fmaf(X00, i.A00, X01 * i.A10);
    r.J01 = i.J01 + __builtin_fmaf(X00, i.A01, X01 * i.A11);
    r.J11 = i.J11 + __builtin_fmaf(X10, i.A01, X11 * i.A11);
    return r;
}

// (h, sigma) -> (a, scale); deterministic, so phase-1 and phase-4 recomputes agree.
__device__ __forceinline__ float2 cvt_asc(float h, float sg)
{
    float ee = fexp2(__builtin_fmaf(h, -14.4269504088896f, 7.2134752044448f));
    float a  = __builtin_fmaf(0.5f, frcp(1.0f + ee), 0.5f);
    float sc = fmaxf(100.0f * sg, 1.0f);
    return make_float2(a, sc);
}

// Append one timestep (later) to accumulated element E (earlier), using the step's
// rank-1 structure (Sherman-Morrison).
__device__ __forceinline__ void append_step(Elt& E, float z, float h, float sg)
{
    float2 ac = cvt_asc(h, sg);
    float a = ac.x, sc = ac.y;
    float q  = 0.1f * sc;
    float r  = sc + 1e-6f;                 // effective R (matches ref's S+1e-6)
    float Sinv = frcp(q + r);
    float u = q * Sinv;
    float v = r * Sinv;

    // w = [1, a];  cw = C w ; g = Sinv * cw ; D = I + g w^T
    float cw0 = __builtin_fmaf(a, E.C01, E.C00);
    float cw1 = __builtin_fmaf(a, E.C11, E.C01);
    float g0 = Sinv * cw0, g1 = Sinv * cw1;
    float rho = frcp(__builtin_fmaf(a, g1, 1.0f + g0));   // 1/(1 + w.g)
    float gp0 = rho * g0, gp1 = rho * g1;

    float s0 = __builtin_fmaf(a, E.A10, E.A00);           // s = A^T w
    float s1 = __builtin_fmaf(a, E.A11, E.A01);

    float wb0  = __builtin_fmaf(a, E.b1, E.b0);           // w . b (old)
    float beta = Sinv * (z - wb0);
    float bp0  = __builtin_fmaf(z, g0, E.b0);             // b + z g  (= b + C eta_s)
    float bp1  = __builtin_fmaf(z, g1, E.b1);

    // A_new = A_s (A - gp s^T),  A_s = [[v, v a],[0,1]]
    float N00 = __builtin_fmaf(-gp0, s0, E.A00);
    float N01 = __builtin_fmaf(-gp0, s1, E.A01);
    float N10 = __builtin_fmaf(-gp1, s0, E.A10);
    float N11 = __builtin_fmaf(-gp1, s1, E.A11);
    float A00n = v * __builtin_fmaf(a, N10, N00);
    float A01n = v * __builtin_fmaf(a, N11, N01);
    // b_new = A_s (bp - gp (w.bp)) + [u z, 0]
    float wbp = __builtin_fmaf(a, bp1, bp0);
    float t0b = __builtin_fmaf(-gp0, wbp, bp0);
    float t1b = __builtin_fmaf(-gp1, wbp, bp1);
    float b0n = __builtin_fmaf(v, __builtin_fmaf(a, t1b, t0b), u * z);
    // C_new = A_s (C - gp cw^T) A_s^T + diag(v q, q)
    float M00 = __builtin_fmaf(-gp0, cw0, E.C00);
    float M01 = __builtin_fmaf(-gp0, cw1, E.C01);
    float M11 = __builtin_fmaf(-gp1, cw1, E.C11);
    float tc0 = __builtin_fmaf(a, M01, M00);
    float tc1 = __builtin_fmaf(a, M11, M01);
    float C00n = v * __builtin_fmaf(v, __builtin_fmaf(a, tc1, tc0), q);
    float C01n = v * tc1;
    float C11n = M11 + q;
    // eta_new = eta + beta*rho * s ;  J_new = J + rho*Sinv * s s^T
    float br  = beta * rho;
    float e0n = __builtin_fmaf(br, s0, E.e0);
    float e1n = __builtin_fmaf(br, s1, E.e1);
    float kap = rho * Sinv;
    float ks0 = kap * s0, ks1 = kap * s1;
    float J00n = __builtin_fmaf(ks0, s0, E.J00);
    float J01n = __builtin_fmaf(ks0, s1, E.J01);
    float J11n = __builtin_fmaf(ks1, s1, E.J11);

    E.A00 = A00n; E.A01 = A01n; E.A10 = N10; E.A11 = N11;
    E.b0 = b0n;  E.b1 = t1b;
    E.C00 = C00n; E.C01 = C01n; E.C11 = C11n;
    E.e0 = e0n;  E.e1 = e1n;
    E.J00 = J00n; E.J01 = J01n; E.J11 = J11n;
}

__device__ __forceinline__ Elt shfl_up_elt(const Elt& x, int d)
{
    Elt r;
    r.A00 = __shfl_up(x.A00, d, 64); r.A01 = __shfl_up(x.A01, d, 64);
    r.A10 = __shfl_up(x.A10, d, 64); r.A11 = __shfl_up(x.A11, d, 64);
    r.b0  = __shfl_up(x.b0,  d, 64); r.b1  = __shfl_up(x.b1,  d, 64);
    r.C00 = __shfl_up(x.C00, d, 64); r.C01 = __shfl_up(x.C01, d, 64);
    r.C11 = __shfl_up(x.C11, d, 64);
    r.e0  = __shfl_up(x.e0,  d, 64); r.e1  = __shfl_up(x.e1,  d, 64);
    r.J00 = __shfl_up(x.J00, d, 64); r.J01 = __shfl_up(x.J01, d, 64);
    r.J11 = __shfl_up(x.J11, d, 64);
    return r;
}

__device__ __forceinline__ void replay_step(float z, float a, float sc,
        float& x0, float& x1, float& p00, float& p01, float& p11)
{
    float q  = 0.1f * sc;
    float rp = sc + 1e-6f;
    float qr = q + rp;
    float tA = __builtin_fmaf(a + a, p01, p00);
    float tB = __builtin_fmaf(a * a, p11, qr);
    float Seff = tA + tB;
    float Sinv = frcp(Seff);
    float pp00 = Seff - rp;
    float pp01 = __builtin_fmaf(a, p11, p01);
    float pp11 = p11 + q;
    float K0 = pp00 * Sinv, K1 = pp01 * Sinv;
    float xp0 = __builtin_fmaf(a, x1, x0);
    float y = z - xp0;
    x0 = __builtin_fmaf(K0, y, xp0);
    x1 = __builtin_fmaf(K1, y, x1);
    p00 = __builtin_fmaf(-K0, pp00, pp00);
    p01 = __builtin_fmaf(-K0, pp01, pp01);
    p11 = __builtin_fmaf(-K1, pp01, pp11);
}

__global__ __launch_bounds__(64)
void ekf_kernel(const float* __restrict__ price,
                const float* __restrict__ hurst,
                const float* __restrict__ sigv,
                float* __restrict__ out)
{
    // Output staging only: 16 local steps x 64 lanes, padded stride 65. 8.45 KiB.
    // Reused for both 16-step halves (single wave per block -> lockstep, no barrier).
    __shared__ float2 xlds[16][65];

    const int row  = blockIdx.x;            // one row per 64-thread block (one wave)
    const int lane = threadIdx.x;

    const float4* __restrict__ pr4 = (const float4*)(price + (size_t)row * NT) + lane * NC4;
    const float4* __restrict__ hu4 = (const float4*)(hurst + (size_t)row * NT) + lane * NC4;
    const float4* __restrict__ sg4 = (const float4*)(sigv  + (size_t)row * NT) + lane * NC4;

    // ---------- Phase 1: batch-load the whole segment, build its element ----------
    float z0l, z1l;
    Elt E;
    E.A00 = 1.0f; E.A01 = 0.0f; E.A10 = 0.0f; E.A11 = 1.0f;
    E.b0 = 0.0f; E.b1 = 0.0f;
    E.C00 = 0.0f; E.C01 = 0.0f; E.C11 = 0.0f;
    E.e0 = 0.0f; E.e1 = 0.0f;
    E.J00 = 0.0f; E.J01 = 0.0f; E.J11 = 0.0f;
    {
        float4 zb[NC4], hb[NC4], sb[NC4];
#pragma unroll
        for (int c = 0; c < NC4; ++c) zb[c] = pr4[c];
#pragma unroll
        for (int c = 0; c < NC4; ++c) hb[c] = hu4[c];
#pragma unroll
        for (int c = 0; c < NC4; ++c) sb[c] = sg4[c];

        z0l = zb[0].x; z1l = zb[0].y;       // lane 0's copies give m0

#pragma unroll
        for (int c = 0; c < NC4; ++c) {
            append_step(E, zb[c].x, hb[c].x, sb[c].x);
            append_step(E, zb[c].y, hb[c].y, sb[c].y);
            append_step(E, zb[c].z, hb[c].z, sb[c].z);
            append_step(E, zb[c].w, hb[c].w, sb[c].w);
        }
    }

    // ---------- Phase 2: inclusive wave scan over the 64 segment elements ----------
#pragma unroll
    for (int d = 1; d < 64; d <<= 1) {
        Elt o = shfl_up_elt(E, d);
        Elt c = combine(o, E);
        bool p = (lane >= d);
        E.A00 = p ? c.A00 : E.A00; E.A01 = p ? c.A01 : E.A01;
        E.A10 = p ? c.A10 : E.A10; E.A11 = p ? c.A11 : E.A11;
        E.b0  = p ? c.b0  : E.b0;  E.b1  = p ? c.b1  : E.b1;
        E.C00 = p ? c.C00 : E.C00; E.C01 = p ? c.C01 : E.C01;
        E.C11 = p ? c.C11 : E.C11;
        E.e0  = p ? c.e0  : E.e0;  E.e1  = p ? c.e1  : E.e1;
        E.J00 = p ? c.J00 : E.J00; E.J01 = p ? c.J01 : E.J01;
        E.J11 = p ? c.J11 : E.J11;
    }

    // Exclusive prefix: element covering steps [0, 32*lane)
    Elt ex = shfl_up_elt(E, 1);
    {
        bool l0 = (lane == 0);              // identity element for lane 0
        ex.A00 = l0 ? 1.0f : ex.A00; ex.A01 = l0 ? 0.0f : ex.A01;
        ex.A10 = l0 ? 0.0f : ex.A10; ex.A11 = l0 ? 1.0f : ex.A11;
        ex.b0  = l0 ? 0.0f : ex.b0;  ex.b1  = l0 ? 0.0f : ex.b1;
        ex.C00 = l0 ? 0.0f : ex.C00; ex.C01 = l0 ? 0.0f : ex.C01;
        ex.C11 = l0 ? 0.0f : ex.C11;
        ex.e0  = l0 ? 0.0f : ex.e0;  ex.e1  = l0 ? 0.0f : ex.e1;
        ex.J00 = l0 ? 0.0f : ex.J00; ex.J01 = l0 ? 0.0f : ex.J01;
        ex.J11 = l0 ? 0.0f : ex.J11;
    }

    // ---------- Phase 3: boundary state from prior (m0, P0 = I) ----------
    float m00 = __shfl(z0l, 0, 64);
    float m01 = __shfl(z1l, 0, 64) - m00;   // v0 = (z1 - z0)/dt, dt = 1

    // apply ex to (m0, I): D = I + J_ex ; E1 = A_ex D^-1
    float D00 = 1.0f + ex.J00, D01 = ex.J01, D11 = 1.0f + ex.J11;
    float idet = frcp(__builtin_fmaf(D00, D11, -D01 * D01));
    float V00 =  D11 * idet, V01 = -D01 * idet;
    float V10 = -D01 * idet, V11 =  D00 * idet;
    float E00 = __builtin_fmaf(ex.A00, V00, ex.A01 * V10);
    float E01 = __builtin_fmaf(ex.A00, V01, ex.A01 * V11);
    float E10 = __builtin_fmaf(ex.A10, V00, ex.A11 * V10);
    float E11 = __builtin_fmaf(ex.A10, V01, ex.A11 * V11);
    float t0 = m00 + ex.e0, t1 = m01 + ex.e1;
    float x0 = ex.b0 + __builtin_fmaf(E00, t0, E01 * t1);
    float x1 = ex.b1 + __builtin_fmaf(E10, t0, E11 * t1);
    float p00 = ex.C00 + __builtin_fmaf(E00, ex.A00, E01 * ex.A01);
    float p01 = ex.C01 + __builtin_fmaf(E00, ex.A10, E01 * ex.A11);
    float p11 = ex.C11 + __builtin_fmaf(E10, ex.A10, E11 * ex.A11);

    // ---------- Phase 4: replay in two 16-step halves through the 8.4 KB LDS buffer ----------
    float2* __restrict__ op2 = (float2*)(out + (size_t)row * (size_t)NT * 2);

#pragma unroll
    for (int half = 0; half < 2; ++half) {
        // reload this half's inputs (cache-warm), 12 batched dwordx4 loads
        float4 zh[4], hh[4], sh[4];
#pragma unroll
        for (int j = 0; j < 4; ++j) zh[j] = pr4[4 * half + j];
#pragma unroll
        for (int j = 0; j < 4; ++j) hh[j] = hu4[4 * half + j];
#pragma unroll
        for (int j = 0; j < 4; ++j) sh[j] = sg4[4 * half + j];

#pragma unroll
        for (int j = 0; j < 4; ++j) {
            float2 a0 = cvt_asc(hh[j].x, sh[j].x);
            replay_step(zh[j].x, a0.x, a0.y, x0, x1, p00, p01, p11);
            xlds[4 * j + 0][lane] = make_float2(x0, x1);
            float2 a1 = cvt_asc(hh[j].y, sh[j].y);
            replay_step(zh[j].y, a1.x, a1.y, x0, x1, p00, p01, p11);
            xlds[4 * j + 1][lane] = make_float2(x0, x1);
            float2 a2 = cvt_asc(hh[j].z, sh[j].z);
            replay_step(zh[j].z, a2.x, a2.y, x0, x1, p00, p01, p11);
            xlds[4 * j + 2][lane] = make_float2(x0, x1);
            float2 a3 = cvt_asc(hh[j].w, sh[j].w);
            replay_step(zh[j].w, a3.x, a3.y, x0, x1, p00, p01, p11);
            xlds[4 * j + 3][lane] = make_float2(x0, x1);
        }

        // drain: element e = owner*32 + half*16 + k lives at xlds[k][owner].
        // n enumerates the 1024 elements of this half; 16-float2 runs stay contiguous.
#pragma unroll
        for (int w = 0; w < 16; ++w) {
            int n = w * 64 + lane;
            int e = ((n >> 4) << 5) + (half << 4) + (n & 15);
            op2[e] = xlds[n & 15][n >> 4];
        }
    }
}

extern "C" void kernel_launch(void* const* d_in, const int* in_sizes, int n_in,
                              void* d_out, int out_size, void* d_ws, size_t ws_size,
                              hipStream_t stream)
{
    const float* price = (const float*)d_in[0];
    const float* hurst = (const float*)d_in[1];
    const float* sigv  = (const float*)d_in[2];
    float* out = (float*)d_out;

    dim3 grid(NB), block(64);
    hipLaunchKernelGGL(ekf_kernel, grid, block, 0, stream, price, hurst, sigv, out);
}

// Round 5
// 278.016 us; speedup vs baseline: 1.5041x; 1.1950x over previous
//
#include <hip/hip_runtime.h>

// DifferentiableEKF, temporally parallelized (Sarkka & Garcia-Fernandez associative
// filtering elements). B=8192 rows, T=2048 steps.
//
// R5: R2's proven dataflow (LDS stages (a,scale) then is overwritten by (x0,x1);
// price-only re-read; coalesced drain) but with TWO waves per row (128-thread block,
// 16 steps per thread). Same ~17KB LDS now carries 2 waves -> 2x waves/CU under
// either residency-cap hypothesis (LDS-capped or blocks/CU-capped), and the serial
// append/replay chains halve (16 vs 32 steps). One LDS-mediated cross-wave scan hop.

#define NB 8192
#define NT 2048
#define TPB 128     // threads per block = 2 waves
#define SEG 16      // timesteps per thread
#define NC4 4       // float4 chunks per thread (SEG/4)
#define LSTRIDE 130 // float2 stride for xlds rows (2-way on own-slot access, free)

__device__ __forceinline__ float frcp(float x)  { return __builtin_amdgcn_rcpf(x); }
__device__ __forceinline__ float fexp2(float x) { return __builtin_amdgcn_exp2f(x); }

// Filtering element: posterior given segment obs as function of prior (m,P):
//   m' = A (I + P J)^-1 (m + P eta) + b ;  P' = A (I + P J)^-1 P A^T + C
struct Elt {
    float A00, A01, A10, A11;
    float b0, b1;
    float C00, C01, C11;   // symmetric
    float e0, e1;          // eta
    float J00, J01, J11;   // symmetric
};

// General associative combine: i = earlier, j = later.
__device__ __forceinline__ Elt combine(const Elt& i, const Elt& j)
{
    // D = I + C_i J_j   (det >= 1: products of PSD matrices)
    float D00 = 1.0f + __builtin_fmaf(i.C00, j.J00, i.C01 * j.J01);
    float D01 =        __builtin_fmaf(i.C00, j.J01, i.C01 * j.J11);
    float D10 =        __builtin_fmaf(i.C01, j.J00, i.C11 * j.J01);
    float D11 = 1.0f + __builtin_fmaf(i.C01, j.J01, i.C11 * j.J11);
    float idet = frcp(__builtin_fmaf(D00, D11, -D01 * D10));
    float V00 =  D11 * idet, V01 = -D01 * idet;
    float V10 = -D10 * idet, V11 =  D00 * idet;          // V = D^-1
    // E = A_j V
    float E00 = __builtin_fmaf(j.A00, V00, j.A01 * V10);
    float E01 = __builtin_fmaf(j.A00, V01, j.A01 * V11);
    float E10 = __builtin_fmaf(j.A10, V00, j.A11 * V10);
    float E11 = __builtin_fmaf(j.A10, V01, j.A11 * V11);
    Elt r;
    // A = E A_i
    r.A00 = __builtin_fmaf(E00, i.A00, E01 * i.A10);
    r.A01 = __builtin_fmaf(E00, i.A01, E01 * i.A11);
    r.A10 = __builtin_fmaf(E10, i.A00, E11 * i.A10);
    r.A11 = __builtin_fmaf(E10, i.A01, E11 * i.A11);
    // b = E (b_i + C_i eta_j) + b_j
    float t0 = i.b0 + __builtin_fmaf(i.C00, j.e0, i.C01 * j.e1);
    float t1 = i.b1 + __builtin_fmaf(i.C01, j.e0, i.C11 * j.e1);
    r.b0 = j.b0 + __builtin_fmaf(E00, t0, E01 * t1);
    r.b1 = j.b1 + __builtin_fmaf(E10, t0, E11 * t1);
    // C = E C_i A_j^T + C_j   (symmetric)
    float T00 = __builtin_fmaf(E00, i.C00, E01 * i.C01);
    float T01 = __builtin_fmaf(E00, i.C01, E01 * i.C11);
    float T10 = __builtin_fmaf(E10, i.C00, E11 * i.C01);
    float T11 = __builtin_fmaf(E10, i.C01, E11 * i.C11);
    r.C00 = j.C00 + __builtin_fmaf(T00, j.A00, T01 * j.A01);
    r.C01 = j.C01 + __builtin_fmaf(T00, j.A10, T01 * j.A11);
    r.C11 = j.C11 + __builtin_fmaf(T10, j.A10, T11 * j.A11);
    // eta = A_i^T V^T (eta_j - J_j b_i) + eta_i
    float u0 = j.e0 - __builtin_fmaf(j.J00, i.b0, j.J01 * i.b1);
    float u1 = j.e1 - __builtin_fmaf(j.J01, i.b0, j.J11 * i.b1);
    float w0 = __builtin_fmaf(V00, u0, V10 * u1);
    float w1 = __builtin_fmaf(V01, u0, V11 * u1);
    r.e0 = i.e0 + __builtin_fmaf(i.A00, w0, i.A10 * w1);
    r.e1 = i.e1 + __builtin_fmaf(i.A01, w0, i.A11 * w1);
    // J = A_i^T V^T J_j A_i + J_i   (symmetric)
    float W00 = __builtin_fmaf(V00, j.J00, V10 * j.J01);
    float W01 = __builtin_fmaf(V00, j.J01, V10 * j.J11);
    float W10 = __builtin_fmaf(V01, j.J00, V11 * j.J01);
    float W11 = __builtin_fmaf(V01, j.J01, V11 * j.J11);
    float X00 = __builtin_fmaf(i.A00, W00, i.A10 * W10);
    float X01 = __builtin_fmaf(i.A00, W01, i.A10 * W11);
    float X10 = __builtin_fmaf(i.A01, W00, i.A11 * W10);
    float X11 = __builtin_fmaf(i.A01, W01, i.A11 * W11);
    r.J00 = i.J00 + __builtin_fmaf(X00, i.A00, X01 * i.A10);
    r.J01 = i.J01 + __builtin_fmaf(X00, i.A01, X01 * i.A11);
    r.J11 = i.J11 + __builtin_fmaf(X10, i.A01, X11 * i.A11);
    return r;
}

// Append one timestep (later) to accumulated element E (earlier), using the step's
// rank-1 structure (Sherman-Morrison). Also emits (a, scale) for the replay.
__device__ __forceinline__ void append_step(Elt& E, float z, float h, float sg,
                                            float& a_out, float& sc_out)
{
    // a = 0.5 + 0.5*sigmoid(10h-5) ; exp(5-10h) via exp2
    float ee = fexp2(__builtin_fmaf(h, -14.4269504088896f, 7.2134752044448f));
    float a  = __builtin_fmaf(0.5f, frcp(1.0f + ee), 0.5f);
    float sc = fmaxf(100.0f * sg, 1.0f);
    float q  = 0.1f * sc;
    float r  = sc + 1e-6f;                 // effective R (matches ref's S+1e-6)
    float Sinv = frcp(q + r);
    float u = q * Sinv;
    float v = r * Sinv;
    a_out = a; sc_out = sc;

    // w = [1, a];  cw = C w ; g = Sinv * cw ; D = I + g w^T
    float cw0 = __builtin_fmaf(a, E.C01, E.C00);
    float cw1 = __builtin_fmaf(a, E.C11, E.C01);
    float g0 = Sinv * cw0, g1 = Sinv * cw1;
    float rho = frcp(__builtin_fmaf(a, g1, 1.0f + g0));   // 1/(1 + w.g)
    float gp0 = rho * g0, gp1 = rho * g1;

    float s0 = __builtin_fmaf(a, E.A10, E.A00);           // s = A^T w
    float s1 = __builtin_fmaf(a, E.A11, E.A01);

    float wb0  = __builtin_fmaf(a, E.b1, E.b0);           // w . b (old)
    float beta = Sinv * (z - wb0);
    float bp0  = __builtin_fmaf(z, g0, E.b0);             // b + z g  (= b + C eta_s)
    float bp1  = __builtin_fmaf(z, g1, E.b1);

    // A_new = A_s (A - gp s^T),  A_s = [[v, v a],[0,1]]
    float N00 = __builtin_fmaf(-gp0, s0, E.A00);
    float N01 = __builtin_fmaf(-gp0, s1, E.A01);
    float N10 = __builtin_fmaf(-gp1, s0, E.A10);
    float N11 = __builtin_fmaf(-gp1, s1, E.A11);
    float A00n = v * __builtin_fmaf(a, N10, N00);
    float A01n = v * __builtin_fmaf(a, N11, N01);
    // b_new = A_s (bp - gp (w.bp)) + [u z, 0]
    float wbp = __builtin_fmaf(a, bp1, bp0);
    float t0b = __builtin_fmaf(-gp0, wbp, bp0);
    float t1b = __builtin_fmaf(-gp1, wbp, bp1);
    float b0n = __builtin_fmaf(v, __builtin_fmaf(a, t1b, t0b), u * z);
    // C_new = A_s (C - gp cw^T) A_s^T + diag(v q, q)
    float M00 = __builtin_fmaf(-gp0, cw0, E.C00);
    float M01 = __builtin_fmaf(-gp0, cw1, E.C01);
    float M11 = __builtin_fmaf(-gp1, cw1, E.C11);
    float tc0 = __builtin_fmaf(a, M01, M00);
    float tc1 = __builtin_fmaf(a, M11, M01);
    float C00n = v * __builtin_fmaf(v, __builtin_fmaf(a, tc1, tc0), q);
    float C01n = v * tc1;
    float C11n = M11 + q;
    // eta_new = eta + beta*rho * s ;  J_new = J + rho*Sinv * s s^T
    float br  = beta * rho;
    float e0n = __builtin_fmaf(br, s0, E.e0);
    float e1n = __builtin_fmaf(br, s1, E.e1);
    float kap = rho * Sinv;
    float ks0 = kap * s0, ks1 = kap * s1;
    float J00n = __builtin_fmaf(ks0, s0, E.J00);
    float J01n = __builtin_fmaf(ks0, s1, E.J01);
    float J11n = __builtin_fmaf(ks1, s1, E.J11);

    E.A00 = A00n; E.A01 = A01n; E.A10 = N10; E.A11 = N11;
    E.b0 = b0n;  E.b1 = t1b;
    E.C00 = C00n; E.C01 = C01n; E.C11 = C11n;
    E.e0 = e0n;  E.e1 = e1n;
    E.J00 = J00n; E.J01 = J01n; E.J11 = J11n;
}

__device__ __forceinline__ Elt shfl_up_elt(const Elt& x, int d)
{
    Elt r;
    r.A00 = __shfl_up(x.A00, d, 64); r.A01 = __shfl_up(x.A01, d, 64);
    r.A10 = __shfl_up(x.A10, d, 64); r.A11 = __shfl_up(x.A11, d, 64);
    r.b0  = __shfl_up(x.b0,  d, 64); r.b1  = __shfl_up(x.b1,  d, 64);
    r.C00 = __shfl_up(x.C00, d, 64); r.C01 = __shfl_up(x.C01, d, 64);
    r.C11 = __shfl_up(x.C11, d, 64);
    r.e0  = __shfl_up(x.e0,  d, 64); r.e1  = __shfl_up(x.e1,  d, 64);
    r.J00 = __shfl_up(x.J00, d, 64); r.J01 = __shfl_up(x.J01, d, 64);
    r.J11 = __shfl_up(x.J11, d, 64);
    return r;
}

__device__ __forceinline__ void replay_step(float z, float a, float sc,
        float& x0, float& x1, float& p00, float& p01, float& p11)
{
    float q  = 0.1f * sc;
    float rp = sc + 1e-6f;
    float qr = q + rp;
    float tA = __builtin_fmaf(a + a, p01, p00);
    float tB = __builtin_fmaf(a * a, p11, qr);
    float Seff = tA + tB;
    float Sinv = frcp(Seff);
    float pp00 = Seff - rp;
    float pp01 = __builtin_fmaf(a, p11, p01);
    float pp11 = p11 + q;
    float K0 = pp00 * Sinv, K1 = pp01 * Sinv;
    float xp0 = __builtin_fmaf(a, x1, x0);
    float y = z - xp0;
    x0 = __builtin_fmaf(K0, y, xp0);
    x1 = __builtin_fmaf(K1, y, x1);
    p00 = __builtin_fmaf(-K0, pp00, pp00);
    p01 = __builtin_fmaf(-K0, pp01, pp01);
    p11 = __builtin_fmaf(-K1, pp01, pp11);
}

__global__ __launch_bounds__(TPB)
void ekf_kernel(const float* __restrict__ price,
                const float* __restrict__ hurst,
                const float* __restrict__ sigv,
                float* __restrict__ out)
{
    // (a,sc) per (local step, thread), overwritten by (x0,x1) during replay, then
    // drained coalesced. 16 x 130 x 8B = 16.6 KiB. Own-slot access is 2-way (free).
    __shared__ float2 xlds[SEG][LSTRIDE];
    __shared__ float  w0tot[14];            // wave 0's inclusive total element

    const int row  = blockIdx.x;            // one row per 128-thread block (2 waves)
    const int tid  = threadIdx.x;
    const int lane = tid & 63;
    const int wav  = tid >> 6;

    const float4* __restrict__ pr4 = (const float4*)(price + (size_t)row * NT) + tid * NC4;
    const float4* __restrict__ hu4 = (const float4*)(hurst + (size_t)row * NT) + tid * NC4;
    const float4* __restrict__ sg4 = (const float4*)(sigv  + (size_t)row * NT) + tid * NC4;

    // m0 from broadcast loads (L1-hit, wave-uniform address)
    const float* __restrict__ prow = price + (size_t)row * NT;
    const float m00 = prow[0];
    const float m01 = prow[1] - m00;        // v0 = (z1 - z0)/dt, dt = 1

    // ---------- Phase 1: batch-load the 16-step segment, build its element ----------
    Elt E;
    E.A00 = 1.0f; E.A01 = 0.0f; E.A10 = 0.0f; E.A11 = 1.0f;
    E.b0 = 0.0f; E.b1 = 0.0f;
    E.C00 = 0.0f; E.C01 = 0.0f; E.C11 = 0.0f;
    E.e0 = 0.0f; E.e1 = 0.0f;
    E.J00 = 0.0f; E.J01 = 0.0f; E.J11 = 0.0f;
    {
        float4 zb[NC4], hb[NC4], sb[NC4];
#pragma unroll
        for (int c = 0; c < NC4; ++c) zb[c] = pr4[c];
#pragma unroll
        for (int c = 0; c < NC4; ++c) hb[c] = hu4[c];
#pragma unroll
        for (int c = 0; c < NC4; ++c) sb[c] = sg4[c];

#pragma unroll
        for (int c = 0; c < NC4; ++c) {
            float a0, c0, a1, c1, a2, c2, a3, c3;
            append_step(E, zb[c].x, hb[c].x, sb[c].x, a0, c0);
            append_step(E, zb[c].y, hb[c].y, sb[c].y, a1, c1);
            append_step(E, zb[c].z, hb[c].z, sb[c].z, a2, c2);
            append_step(E, zb[c].w, hb[c].w, sb[c].w, a3, c3);
            const int k = 4 * c;
            xlds[k + 0][tid] = make_float2(a0, c0);
            xlds[k + 1][tid] = make_float2(a1, c1);
            xlds[k + 2][tid] = make_float2(a2, c2);
            xlds[k + 3][tid] = make_float2(a3, c3);
        }
    }

    // ---------- Phase 2a: in-wave inclusive scan (6 shfl rounds) ----------
#pragma unroll
    for (int d = 1; d < 64; d <<= 1) {
        Elt o = shfl_up_elt(E, d);
        Elt c = combine(o, E);
        bool p = (lane >= d);
        E.A00 = p ? c.A00 : E.A00; E.A01 = p ? c.A01 : E.A01;
        E.A10 = p ? c.A10 : E.A10; E.A11 = p ? c.A11 : E.A11;
        E.b0  = p ? c.b0  : E.b0;  E.b1  = p ? c.b1  : E.b1;
        E.C00 = p ? c.C00 : E.C00; E.C01 = p ? c.C01 : E.C01;
        E.C11 = p ? c.C11 : E.C11;
        E.e0  = p ? c.e0  : E.e0;  E.e1  = p ? c.e1  : E.e1;
        E.J00 = p ? c.J00 : E.J00; E.J01 = p ? c.J01 : E.J01;
        E.J11 = p ? c.J11 : E.J11;
    }

    // Publish wave 0's total (its lane 63 inclusive element)
    if (tid == 63) {
        w0tot[0]  = E.A00; w0tot[1]  = E.A01; w0tot[2]  = E.A10; w0tot[3]  = E.A11;
        w0tot[4]  = E.b0;  w0tot[5]  = E.b1;
        w0tot[6]  = E.C00; w0tot[7]  = E.C01; w0tot[8]  = E.C11;
        w0tot[9]  = E.e0;  w0tot[10] = E.e1;
        w0tot[11] = E.J00; w0tot[12] = E.J01; w0tot[13] = E.J11;
    }
    __syncthreads();

    // ---------- Phase 2b: in-wave exclusive, then prepend wave 0's total on wave 1 ----------
    Elt ex = shfl_up_elt(E, 1);
    {
        bool l0 = (lane == 0);              // identity element for lane 0
        ex.A00 = l0 ? 1.0f : ex.A00; ex.A01 = l0 ? 0.0f : ex.A01;
        ex.A10 = l0 ? 0.0f : ex.A10; ex.A11 = l0 ? 1.0f : ex.A11;
        ex.b0  = l0 ? 0.0f : ex.b0;  ex.b1  = l0 ? 0.0f : ex.b1;
        ex.C00 = l0 ? 0.0f : ex.C00; ex.C01 = l0 ? 0.0f : ex.C01;
        ex.C11 = l0 ? 0.0f : ex.C11;
        ex.e0  = l0 ? 0.0f : ex.e0;  ex.e1  = l0 ? 0.0f : ex.e1;
        ex.J00 = l0 ? 0.0f : ex.J00; ex.J01 = l0 ? 0.0f : ex.J01;
        ex.J11 = l0 ? 0.0f : ex.J11;
    }
    if (wav == 1) {                          // wave-uniform branch
        Elt w0;
        w0.A00 = w0tot[0];  w0.A01 = w0tot[1];  w0.A10 = w0tot[2];  w0.A11 = w0tot[3];
        w0.b0  = w0tot[4];  w0.b1  = w0tot[5];
        w0.C00 = w0tot[6];  w0.C01 = w0tot[7];  w0.C11 = w0tot[8];
        w0.e0  = w0tot[9];  w0.e1  = w0tot[10];
        w0.J00 = w0tot[11]; w0.J01 = w0tot[12]; w0.J11 = w0tot[13];
        ex = combine(w0, ex);               // combine(earlier, later); identity-safe
    }

    // ---------- Phase 3: boundary state from prior (m0, P0 = I) ----------
    float D00 = 1.0f + ex.J00, D01 = ex.J01, D11 = 1.0f + ex.J11;
    float idet = frcp(__builtin_fmaf(D00, D11, -D01 * D01));
    float V00 =  D11 * idet, V01 = -D01 * idet;
    float V10 = -D01 * idet, V11 =  D00 * idet;
    float E00 = __builtin_fmaf(ex.A00, V00, ex.A01 * V10);
    float E01 = __builtin_fmaf(ex.A00, V01, ex.A01 * V11);
    float E10 = __builtin_fmaf(ex.A10, V00, ex.A11 * V10);
    float E11 = __builtin_fmaf(ex.A10, V01, ex.A11 * V11);
    float t0 = m00 + ex.e0, t1 = m01 + ex.e1;
    float x0 = ex.b0 + __builtin_fmaf(E00, t0, E01 * t1);
    float x1 = ex.b1 + __builtin_fmaf(E10, t0, E11 * t1);
    float p00 = ex.C00 + __builtin_fmaf(E00, ex.A00, E01 * ex.A01);
    float p01 = ex.C01 + __builtin_fmaf(E00, ex.A10, E01 * ex.A11);
    float p11 = ex.C11 + __builtin_fmaf(E10, ex.A10, E11 * ex.A11);

    // ---------- Phase 4: reload price (batched, cache-warm), replay, stash into LDS ----------
    {
        float4 zb[NC4];
#pragma unroll
        for (int c = 0; c < NC4; ++c) zb[c] = pr4[c];

#pragma unroll
        for (int c = 0; c < NC4; ++c) {
            const int k = 4 * c;
            float2 q0 = xlds[k + 0][tid];
            float2 q1 = xlds[k + 1][tid];
            float2 q2 = xlds[k + 2][tid];
            float2 q3 = xlds[k + 3][tid];

            replay_step(zb[c].x, q0.x, q0.y, x0, x1, p00, p01, p11);
            xlds[k + 0][tid] = make_float2(x0, x1);
            replay_step(zb[c].y, q1.x, q1.y, x0, x1, p00, p01, p11);
            xlds[k + 1][tid] = make_float2(x0, x1);
            replay_step(zb[c].z, q2.x, q2.y, x0, x1, p00, p01, p11);
            xlds[k + 2][tid] = make_float2(x0, x1);
            replay_step(zb[c].w, q3.x, q3.y, x0, x1, p00, p01, p11);
            xlds[k + 3][tid] = make_float2(x0, x1);
        }
    }
    __syncthreads();

    // ---------- Phase 5: coalesced drain — step t lives at xlds[t & 15][t >> 4] ----------
    float2* __restrict__ op2 = (float2*)(out + (size_t)row * (size_t)NT * 2);
#pragma unroll
    for (int w = 0; w < SEG; ++w) {
        int n = w * TPB + tid;
        op2[n] = xlds[n & 15][n >> 4];
    }
}

extern "C" void kernel_launch(void* const* d_in, const int* in_sizes, int n_in,
                              void* d_out, int out_size, void* d_ws, size_t ws_size,
                              hipStream_t stream)
{
    const float* price = (const float*)d_in[0];
    const float* hurst = (const float*)d_in[1];
    const float* sigv  = (const float*)d_in[2];
    float* out = (float*)d_out;

    dim3 grid(NB), block(TPB);
    hipLaunchKernelGGL(ekf_kernel, grid, block, 0, stream, price, hurst, sigv, out);
}